// Round 7
// baseline (269.272 us; speedup 1.0000x reference)
//
#include <hip/hip_runtime.h>
#include <math.h>

#define NUM_LEVELS 16
#define LOG2_T 19
#define TABLE_SIZE (1u << LOG2_T)
#define MASK (TABLE_SIZE - 1u)

typedef float vf2 __attribute__((ext_vector_type(2)));
typedef float vf4 __attribute__((ext_vector_type(4)));

struct Scalings { float s[NUM_LEVELS]; };

__global__ __launch_bounds__(256) void hashenc_kernel(
    const float4* __restrict__ xyzt,
    const float2* __restrict__ table,
    float2* __restrict__ dst,     // scratch [L][N] if use_scratch, else out [N][L]
    Scalings sc,
    int n_pts,
    int bpl,
    int use_scratch)
{
    // XCD-EXCLUSIVE levels: block b lands on XCD (b&7) (round-robin dispatch
    // heuristic, validated rounds 3-4). XCD k owns levels {k, 15-k} and
    // processes ALL points for one level before the next, so each 4MB level
    // slice is fetched from HBM into exactly ONE XCD's L2 and stays resident
    // (~98.5% hit) instead of being replicated into all 8 L2s (round-5 FETCH
    // was 432MB = full replication).
    unsigned b = blockIdx.x;
    unsigned xcd = b & 7u;
    unsigned slot = b >> 3;
    unsigned level = (slot < (unsigned)bpl) ? xcd : (15u - xcd);
    unsigned chunk = (slot < (unsigned)bpl) ? slot : slot - (unsigned)bpl;

    int n = (int)(chunk * 256u + threadIdx.x);
    if (n >= n_pts || level >= NUM_LEVELS) return;

    float4 p = xyzt[n];
    float s = sc.s[level];

    float sx = p.x * s, sy = p.y * s, sz = p.z * s, st = p.w * s;
    float fx = floorf(sx), fy = floorf(sy), fz = floorf(sz), ft = floorf(st);
    float ox = sx - fx, oy = sy - fy, oz = sz - fz, ot = st - ft;

    const unsigned P1 = 2654435761u, P2 = 805459861u, P3 = 3674653429u;
    unsigned xf = (unsigned)fx, xc = (unsigned)ceilf(sx);
    unsigned my_[2] = { (unsigned)fy * P1, (unsigned)ceilf(sy) * P1 };
    unsigned mz_[2] = { (unsigned)fz * P2, (unsigned)ceilf(sz) * P2 };
    unsigned mt_[2] = { (unsigned)ft * P3, (unsigned)ceilf(st) * P3 };
    float wx0 = 1.0f - ox, wx1 = ox;
    float wy_[2] = { 1.0f - oy, oy };
    float wz_[2] = { 1.0f - oz, oz };
    float wt_[2] = { 1.0f - ot, ot };

    unsigned rest[8]; float wrest[8];
    #pragma unroll
    for (int r = 0; r < 8; ++r) {
        rest[r]  = my_[r & 1] ^ mz_[(r >> 1) & 1] ^ mt_[(r >> 2) & 1];
        wrest[r] = wy_[r & 1] * wz_[(r >> 1) & 1] * wt_[(r >> 2) & 1];
    }

    unsigned base = level << LOG2_T;
    float a0 = 0.0f, a1 = 0.0f;

    // x-prime is 1: when xf is even and xc==xf+1, both x-corners of each pair
    // live in the same 16B table block -> one float4 gather (round-5 win).
    bool merge = ((xf & 1u) == 0u) && (xc == xf + 1u);
    if (merge) {
        const float4* t4 = (const float4*)table;
        #pragma unroll
        for (int r = 0; r < 8; ++r) {
            unsigned g = ((xf ^ rest[r]) & MASK) + base;
            float4 v = t4[g >> 1];
            bool hi = (g & 1u) != 0u;
            float c0x = hi ? v.z : v.x, c0y = hi ? v.w : v.y;
            float c1x = hi ? v.x : v.z, c1y = hi ? v.y : v.w;
            float wl = wrest[r];
            a0 = fmaf(wl, fmaf(wx0, c0x, wx1 * c1x), a0);
            a1 = fmaf(wl, fmaf(wx0, c0y, wx1 * c1y), a1);
        }
    } else {
        #pragma unroll
        for (int r = 0; r < 8; ++r) {
            unsigned g0 = ((xf ^ rest[r]) & MASK) + base;
            unsigned g1 = ((xc ^ rest[r]) & MASK) + base;
            float2 v0 = table[g0];
            float2 v1 = table[g1];
            float wl = wrest[r];
            a0 = fmaf(wl, fmaf(wx0, v0.x, wx1 * v1.x), a0);
            a1 = fmaf(wl, fmaf(wx0, v0.y, wx1 * v1.y), a1);
        }
    }

    if (use_scratch) {
        // Nontemporal: don't let the 32MB scratch stream evict the resident slice.
        vf2 outv = { a0, a1 };
        __builtin_nontemporal_store(outv, (vf2*)&dst[(size_t)level * n_pts + n]);
    } else {
        dst[(size_t)n * NUM_LEVELS + level] = make_float2(a0, a1);
    }
}

// 2 points/thread: float4 NT reads from ws, 256B contiguous NT writes.
__global__ __launch_bounds__(256) void transpose2_kernel(
    const vf4* __restrict__ ws4,   // [L][N/2] float4
    vf4* __restrict__ out,
    int n2)
{
    int t = blockIdx.x * 256 + (int)threadIdx.x;
    if (t >= n2) return;
    vf4 v[NUM_LEVELS];
    #pragma unroll
    for (int l = 0; l < NUM_LEVELS; ++l)
        v[l] = __builtin_nontemporal_load(&ws4[(size_t)l * n2 + t]);
    vf4* o = out + (size_t)(2 * t) * 8;
    #pragma unroll
    for (int i = 0; i < 8; ++i) {
        vf4 w = { v[2 * i].x, v[2 * i].y, v[2 * i + 1].x, v[2 * i + 1].y };
        __builtin_nontemporal_store(w, &o[i]);
    }
    #pragma unroll
    for (int i = 0; i < 8; ++i) {
        vf4 w = { v[2 * i].z, v[2 * i].w, v[2 * i + 1].z, v[2 * i + 1].w };
        __builtin_nontemporal_store(w, &o[8 + i]);
    }
}

__global__ __launch_bounds__(256) void transpose_kernel(
    const float2* __restrict__ ws,
    float4* __restrict__ out,
    int n_pts)
{
    int n = blockIdx.x * 256 + (int)threadIdx.x;
    if (n >= n_pts) return;
    float2 v[NUM_LEVELS];
    #pragma unroll
    for (int l = 0; l < NUM_LEVELS; ++l)
        v[l] = ws[(size_t)l * n_pts + n];
    float4* o = out + (size_t)n * 8;
    #pragma unroll
    for (int i = 0; i < 8; ++i)
        o[i] = make_float4(v[2 * i].x, v[2 * i].y, v[2 * i + 1].x, v[2 * i + 1].y);
}

extern "C" void kernel_launch(void* const* d_in, const int* in_sizes, int n_in,
                              void* d_out, int out_size, void* d_ws, size_t ws_size,
                              hipStream_t stream) {
    const float4* xyzt  = (const float4*)d_in[0];
    const float2* table = (const float2*)d_in[1];
    int n_pts = in_sizes[0] / 4;

    // Mirror numpy's float64 computation of _SCALINGS exactly.
    Scalings sc;
    double growth = exp((log(256.0) - log(16.0)) / 15.0);
    for (int l = 0; l < NUM_LEVELS; ++l)
        sc.s[l] = (float)floor(16.0 * pow(growth, (double)l));

    int block = 256;
    int bpl = (n_pts + block - 1) / block;
    int grid = 8 * 2 * bpl;   // 8 XCDs x 2 levels each x bpl chunks

    size_t need = (size_t)NUM_LEVELS * n_pts * sizeof(float2);
    int use_scratch = (d_ws != nullptr && ws_size >= need) ? 1 : 0;

    float2* dst = use_scratch ? (float2*)d_ws : (float2*)d_out;
    hashenc_kernel<<<grid, block, 0, stream>>>(xyzt, table, dst, sc, n_pts, bpl, use_scratch);

    if (use_scratch) {
        if ((n_pts & 1) == 0) {
            int n2 = n_pts / 2;
            int g2 = (n2 + block - 1) / block;
            transpose2_kernel<<<g2, block, 0, stream>>>((const vf4*)d_ws, (vf4*)d_out, n2);
        } else {
            transpose_kernel<<<bpl, block, 0, stream>>>((const float2*)d_ws, (float4*)d_out, n_pts);
        }
    }
}

// Round 8
// 218.282 us; speedup vs baseline: 1.2336x; 1.2336x over previous
//
#include <hip/hip_runtime.h>
#include <math.h>

#define NUM_LEVELS 16
#define LOG2_T 19
#define TABLE_SIZE (1u << LOG2_T)
#define MASK (TABLE_SIZE - 1u)

typedef float vf2 __attribute__((ext_vector_type(2)));
typedef float vf4 __attribute__((ext_vector_type(4)));

struct Scalings { float s[NUM_LEVELS]; };

__global__ __launch_bounds__(256) void hashenc_kernel(
    const float4* __restrict__ xyzt,
    const float2* __restrict__ table,
    float2* __restrict__ dst,     // scratch [L][N] if use_scratch, else out [N][L]
    Scalings sc,
    int n_pts,
    int bpl,
    int use_scratch)
{
    // XCD-EXCLUSIVE levels (round-7 win: FETCH 432->134MB): block b lands on
    // XCD (b&7); XCD k owns levels {k, 15-k}, streaming all points through one
    // level before the next, so each 4MB slice is resident in exactly one L2.
    unsigned b = blockIdx.x;
    unsigned xcd = b & 7u;
    unsigned slot = b >> 3;
    unsigned level = (slot < (unsigned)bpl) ? xcd : (15u - xcd);
    unsigned chunk = (slot < (unsigned)bpl) ? slot : slot - (unsigned)bpl;

    int n = (int)(chunk * 256u + threadIdx.x);
    if (n >= n_pts || level >= NUM_LEVELS) return;

    float4 p = xyzt[n];
    float s = sc.s[level];

    float sx = p.x * s, sy = p.y * s, sz = p.z * s, st = p.w * s;
    float fx = floorf(sx), fy = floorf(sy), fz = floorf(sz), ft = floorf(st);
    float ox = sx - fx, oy = sy - fy, oz = sz - fz, ot = st - ft;

    const unsigned P1 = 2654435761u, P2 = 805459861u, P3 = 3674653429u;
    unsigned xf = (unsigned)fx, xc = (unsigned)ceilf(sx);
    unsigned my_[2] = { (unsigned)fy * P1, (unsigned)ceilf(sy) * P1 };
    unsigned mz_[2] = { (unsigned)fz * P2, (unsigned)ceilf(sz) * P2 };
    unsigned mt_[2] = { (unsigned)ft * P3, (unsigned)ceilf(st) * P3 };
    float wx0 = 1.0f - ox, wx1 = ox;
    float wy_[2] = { 1.0f - oy, oy };
    float wz_[2] = { 1.0f - oz, oz };
    float wt_[2] = { 1.0f - ot, ot };

    unsigned rest[8]; float wrest[8];
    #pragma unroll
    for (int r = 0; r < 8; ++r) {
        rest[r]  = my_[r & 1] ^ mz_[(r >> 1) & 1] ^ mt_[(r >> 2) & 1];
        wrest[r] = wy_[r & 1] * wz_[(r >> 1) & 1] * wt_[(r >> 2) & 1];
    }

    unsigned base = level << LOG2_T;
    float a0 = 0.0f, a1 = 0.0f;

    // x-prime is 1: when xf is even and xc==xf+1, both x-corners of each pair
    // live in the same 16B table block -> one float4 gather (round-5 win:
    // 16 -> 12 avg line-requests per point-level).
    bool merge = ((xf & 1u) == 0u) && (xc == xf + 1u);
    if (merge) {
        const float4* t4 = (const float4*)table;
        #pragma unroll
        for (int r = 0; r < 8; ++r) {
            unsigned g = ((xf ^ rest[r]) & MASK) + base;
            float4 v = t4[g >> 1];
            bool hi = (g & 1u) != 0u;
            float c0x = hi ? v.z : v.x, c0y = hi ? v.w : v.y;
            float c1x = hi ? v.x : v.z, c1y = hi ? v.y : v.w;
            float wl = wrest[r];
            a0 = fmaf(wl, fmaf(wx0, c0x, wx1 * c1x), a0);
            a1 = fmaf(wl, fmaf(wx0, c0y, wx1 * c1y), a1);
        }
    } else {
        #pragma unroll
        for (int r = 0; r < 8; ++r) {
            unsigned g0 = ((xf ^ rest[r]) & MASK) + base;
            unsigned g1 = ((xc ^ rest[r]) & MASK) + base;
            float2 v0 = table[g0];
            float2 v1 = table[g1];
            float wl = wrest[r];
            a0 = fmaf(wl, fmaf(wx0, v0.x, wx1 * v1.x), a0);
            a1 = fmaf(wl, fmaf(wx0, v0.y, wx1 * v1.y), a1);
        }
    }

    if (use_scratch) {
        // NT store: scratch stream must not evict the resident table slice.
        vf2 outv = { a0, a1 };
        __builtin_nontemporal_store(outv, (vf2*)&dst[(size_t)level * n_pts + n]);
    } else {
        dst[(size_t)n * NUM_LEVELS + level] = make_float2(a0, a1);
    }
}

// 2 points/thread: PLAIN cached float4 reads (round-7 lesson: NT loads bypass
// L3 and ran at 0.93 TB/s vs 3.8 TB/s cached), 256B contiguous writes.
__global__ __launch_bounds__(256) void transpose2_kernel(
    const float4* __restrict__ ws4,   // [L][N/2] float4
    float4* __restrict__ out,
    int n2)
{
    int t = blockIdx.x * 256 + (int)threadIdx.x;
    if (t >= n2) return;
    float4 v[NUM_LEVELS];
    #pragma unroll
    for (int l = 0; l < NUM_LEVELS; ++l)
        v[l] = ws4[(size_t)l * n2 + t];          // points {2t,2t+1} at level l
    float4* o = out + (size_t)(2 * t) * 8;
    #pragma unroll
    for (int i = 0; i < 8; ++i)
        o[i] = make_float4(v[2 * i].x, v[2 * i].y, v[2 * i + 1].x, v[2 * i + 1].y);
    #pragma unroll
    for (int i = 0; i < 8; ++i)
        o[8 + i] = make_float4(v[2 * i].z, v[2 * i].w, v[2 * i + 1].z, v[2 * i + 1].w);
}

__global__ __launch_bounds__(256) void transpose_kernel(
    const float2* __restrict__ ws,
    float4* __restrict__ out,
    int n_pts)
{
    int n = blockIdx.x * 256 + (int)threadIdx.x;
    if (n >= n_pts) return;
    float2 v[NUM_LEVELS];
    #pragma unroll
    for (int l = 0; l < NUM_LEVELS; ++l)
        v[l] = ws[(size_t)l * n_pts + n];
    float4* o = out + (size_t)n * 8;
    #pragma unroll
    for (int i = 0; i < 8; ++i)
        o[i] = make_float4(v[2 * i].x, v[2 * i].y, v[2 * i + 1].x, v[2 * i + 1].y);
}

extern "C" void kernel_launch(void* const* d_in, const int* in_sizes, int n_in,
                              void* d_out, int out_size, void* d_ws, size_t ws_size,
                              hipStream_t stream) {
    const float4* xyzt  = (const float4*)d_in[0];
    const float2* table = (const float2*)d_in[1];
    int n_pts = in_sizes[0] / 4;

    // Mirror numpy's float64 computation of _SCALINGS exactly.
    Scalings sc;
    double growth = exp((log(256.0) - log(16.0)) / 15.0);
    for (int l = 0; l < NUM_LEVELS; ++l)
        sc.s[l] = (float)floor(16.0 * pow(growth, (double)l));

    int block = 256;
    int bpl = (n_pts + block - 1) / block;
    int grid = 8 * 2 * bpl;   // 8 XCDs x 2 levels each x bpl chunks

    size_t need = (size_t)NUM_LEVELS * n_pts * sizeof(float2);
    int use_scratch = (d_ws != nullptr && ws_size >= need) ? 1 : 0;

    float2* dst = use_scratch ? (float2*)d_ws : (float2*)d_out;
    hashenc_kernel<<<grid, block, 0, stream>>>(xyzt, table, dst, sc, n_pts, bpl, use_scratch);

    if (use_scratch) {
        if ((n_pts & 1) == 0) {
            int n2 = n_pts / 2;
            int g2 = (n2 + block - 1) / block;
            transpose2_kernel<<<g2, block, 0, stream>>>((const float4*)d_ws, (float4*)d_out, n2);
        } else {
            transpose_kernel<<<bpl, block, 0, stream>>>((const float2*)d_ws, (float4*)d_out, n_pts);
        }
    }
}